// Round 6
// baseline (99.469 us; speedup 1.0000x reference)
//
#include <hip/hip_runtime.h>

#define CIN  32
#define OCH  64
#define HH   56
#define WW   56
#define BB   4
#define OT   4                  // output channels per block
#define TH   8                  // output rows per block strip
#define NT   448                // threads = 8*56, 7 waves, zero waste
#define CG   8                  // channels per LDS phase
#define CPB  16                 // channels per block (2-way channel split)
#define HALO_H (TH + 2)         // 10
#define HALO_W (WW + 2)         // 58
#define CH_STRIDE (HALO_H * HALO_W)   // 580
#define STAGE (CG * CH_STRIDE)        // 4640
#define IMG  (HH * WW)          // 3136
#define NW   18432              // 64*32*3*3
#define OUTN (BB * OCH * IMG)   // 802816
#define WSOFF 16                // partials start at float offset 16 (64B)

__global__ __launch_bounds__(256) void absmean_reduce(const float* __restrict__ w,
                                                      float* __restrict__ ws) {
    int idx = (blockIdx.x * 256 + threadIdx.x) * 4;   // 18 blocks * 256 * 4 = 18432
    float4 v = *reinterpret_cast<const float4*>(w + idx);
    float s = fabsf(v.x) + fabsf(v.y) + fabsf(v.z) + fabsf(v.w);
    #pragma unroll
    for (int off = 32; off > 0; off >>= 1)
        s += __shfl_down(s, off);
    __shared__ float smem[4];
    int lane = threadIdx.x & 63, wv = threadIdx.x >> 6;
    if (lane == 0) smem[wv] = s;
    __syncthreads();
    if (threadIdx.x == 0)
        atomicAdd(ws, smem[0] + smem[1] + smem[2] + smem[3]);
}

// Block = 448 threads = one 8x56 output strip x 4 output channels x 16 input
// channels (2-way channel split doubles the grid: 896 blocks = 24.5 waves/CU).
// x staged zero-padded in LDS; weights at wave-uniform addresses in uniform
// control flow -> scalar loads. Partial sums stored plain to d_ws.
__global__ __launch_bounds__(NT) void minconv_kernel(const float* __restrict__ x,
                                                     const float* __restrict__ wts,
                                                     float* __restrict__ part) {
    __shared__ float xs[STAGE];         // 18560 B

    const int tid = threadIdx.x;
    const int ht  = blockIdx.x;         // 0..6
    const int o0  = blockIdx.y * OT;    // 0..60
    const int b   = blockIdx.z >> 1;    // 0..3
    const int cs  = blockIdx.z & 1;     // channel split 0/1
    const int c0  = cs * CPB;
    const int h0  = ht * TH;

    const int ph = tid / WW;            // 0..7
    const int pw = tid - ph * WW;       // 0..55

    const float* xb = x + (b * CIN + c0) * IMG;
    const float* wb = wts + o0 * (CIN * 9);

    float acc[OT] = {0.f, 0.f, 0.f, 0.f};

    for (int cg = 0; cg < CPB; cg += CG) {
        __syncthreads();                // protect previous phase's reads
        const float* xc = xb + cg * IMG;
        for (int j = 0; j < 11; ++j) {  // ceil(4640/448)
            int i = tid + j * NT;
            if (i < STAGE) {
                int c  = i / CH_STRIDE;
                int r  = (i - c * CH_STRIDE) / HALO_W;
                int cc = i - c * CH_STRIDE - r * HALO_W;
                int gh = h0 - 1 + r;
                int gw = cc - 1;
                float v = 0.f;
                if ((unsigned)gh < (unsigned)HH && (unsigned)gw < (unsigned)WW)
                    v = xc[c * IMG + gh * WW + gw];
                xs[i] = v;
            }
        }
        __syncthreads();

        const float* xp0 = xs + ph * HALO_W + pw;
        #pragma unroll 4
        for (int c = 0; c < CG; ++c) {
            const float* xp = xp0 + c * CH_STRIDE;
            float xv[9];
            #pragma unroll
            for (int kh = 0; kh < 3; ++kh)
                #pragma unroll
                for (int kw = 0; kw < 3; ++kw)
                    xv[kh * 3 + kw] = xp[kh * HALO_W + kw];
            #pragma unroll
            for (int oo = 0; oo < OT; ++oo) {
                const float* wp = wb + (oo * CIN + c0 + cg + c) * 9;  // uniform
                #pragma unroll
                for (int t = 0; t < 9; ++t)
                    acc[oo] += fminf(xv[t], wp[t]);
            }
        }
    }

    float* pb = part + cs * OUTN + (b * OCH + o0) * IMG + (h0 + ph) * WW + pw;
    #pragma unroll
    for (int oo = 0; oo < OT; ++oo)
        pb[oo * IMG] = acc[oo];
}

// out[i] = mu * (part0[i] + part1[i]); float4 over 802816 elems.
__global__ __launch_bounds__(256) void combine_kernel(const float* __restrict__ ws,
                                                      float* __restrict__ out) {
    const float mu = ws[0] * (1.0f / (float)NW);
    const float* p = ws + WSOFF;
    int i = (blockIdx.x * 256 + threadIdx.x) * 4;   // 784 blocks, exact
    float4 a = *reinterpret_cast<const float4*>(p + i);
    float4 c = *reinterpret_cast<const float4*>(p + OUTN + i);
    float4 r;
    r.x = mu * (a.x + c.x);
    r.y = mu * (a.y + c.y);
    r.z = mu * (a.z + c.z);
    r.w = mu * (a.w + c.w);
    *reinterpret_cast<float4*>(out + i) = r;
}

extern "C" void kernel_launch(void* const* d_in, const int* in_sizes, int n_in,
                              void* d_out, int out_size, void* d_ws, size_t ws_size,
                              hipStream_t stream) {
    const float* x   = (const float*)d_in[0];   // 4*32*56*56
    const float* w   = (const float*)d_in[1];   // 64*32*3*3
    float*       out = (float*)d_out;           // 4*64*56*56
    float*       ws  = (float*)d_ws;

    hipMemsetAsync(ws, 0, sizeof(float), stream);
    absmean_reduce<<<NW / (256 * 4), 256, 0, stream>>>(w, ws);
    dim3 grid(HH / TH, OCH / OT, BB * 2);       // 7 x 16 x 8 = 896 blocks
    minconv_kernel<<<grid, NT, 0, stream>>>(x, w, ws + WSOFF);
    combine_kernel<<<OUTN / (256 * 4), 256, 0, stream>>>(ws, out);
}

// Round 7
// 91.735 us; speedup vs baseline: 1.0843x; 1.0843x over previous
//
#include <hip/hip_runtime.h>

#define CIN  32
#define OCH  64
#define HH   56
#define WW   56
#define BB   4
#define OT   4                  // output channels per block
#define TH   8                  // output rows per block strip
#define NT   448                // threads = 8*56, 7 waves, zero waste
#define CG   8                  // channels per LDS phase
#define CPB  16                 // channels per block (2-way channel split)
#define HALO_H (TH + 2)         // 10
#define HALO_W (WW + 2)         // 58
#define CH_STRIDE (HALO_H * HALO_W)   // 580
#define STAGE (CG * CH_STRIDE)        // 4640
#define NJ   11                       // ceil(4640/448)
#define IMG  (HH * WW)          // 3136
#define NW   18432              // 64*32*3*3
#define OUTN (BB * OCH * IMG)   // 802816
#define WSOFF 16                // partials start at float offset 16 (64B)

// v_min_f32 with the weight FORCED into an SGPR (src0). Bypasses llvm.minnum
// (no NaN-canonicalization ops) and guarantees scalar weight residency.
__device__ __forceinline__ float min_ws(float x, float w) {
    float r;
    asm("v_min_f32 %0, %2, %1" : "=v"(r) : "v"(x), "s"(w));
    return r;
}

__global__ __launch_bounds__(256) void absmean_reduce(const float* __restrict__ w,
                                                      float* __restrict__ ws) {
    int idx = (blockIdx.x * 256 + threadIdx.x) * 4;   // 18 blocks * 256 * 4 = 18432
    float4 v = *reinterpret_cast<const float4*>(w + idx);
    float s = fabsf(v.x) + fabsf(v.y) + fabsf(v.z) + fabsf(v.w);
    #pragma unroll
    for (int off = 32; off > 0; off >>= 1)
        s += __shfl_down(s, off);
    __shared__ float smem[4];
    int lane = threadIdx.x & 63, wv = threadIdx.x >> 6;
    if (lane == 0) smem[wv] = s;
    __syncthreads();
    if (threadIdx.x == 0)
        atomicAdd(ws, smem[0] + smem[1] + smem[2] + smem[3]);
}

// Block = 448 threads = one 8x56 output strip x 4 output channels x 16 input
// channels. x staged zero-padded in LDS; weights reach v_min_f32 as SGPR
// operands (scalar loads). Partial sums stored plain to d_ws.
__global__ __launch_bounds__(NT) void minconv_kernel(const float* __restrict__ x,
                                                     const float* __restrict__ wts,
                                                     float* __restrict__ part) {
    __shared__ float xs[STAGE];         // 18560 B

    const int tid = threadIdx.x;
    const int ht  = blockIdx.x;         // 0..6
    const int o0  = blockIdx.y * OT;    // 0..60
    const int b   = blockIdx.z >> 1;    // 0..3
    const int cs  = blockIdx.z & 1;     // channel split 0/1
    const int c0  = cs * CPB;
    const int h0  = ht * TH;

    const int ph = tid / WW;            // 0..7
    const int pw = tid - ph * WW;       // 0..55

    const float* xb = x + (b * CIN + c0) * IMG;
    const float* wb = wts + o0 * (CIN * 9);

    // staging address precompute (reused across both phases)
    int  srel[NJ];
    bool sok[NJ];
    #pragma unroll
    for (int j = 0; j < NJ; ++j) {
        int i  = tid + j * NT;
        int c  = i / CH_STRIDE;
        int r  = (i - c * CH_STRIDE) / HALO_W;
        int cc = i - c * CH_STRIDE - r * HALO_W;
        int gh = h0 - 1 + r;
        int gw = cc - 1;
        sok[j]  = (i < STAGE) & ((unsigned)gh < (unsigned)HH) & ((unsigned)gw < (unsigned)WW);
        srel[j] = c * IMG + gh * WW + gw;
    }

    float acc[OT] = {0.f, 0.f, 0.f, 0.f};

    for (int cg = 0; cg < CPB; cg += CG) {
        __syncthreads();                // protect previous phase's reads
        const float* xc = xb + cg * IMG;
        #pragma unroll
        for (int j = 0; j < NJ; ++j) {
            float v = 0.f;
            if (sok[j]) v = xc[srel[j]];
            int i = tid + j * NT;
            if (j < NJ - 1) xs[i] = v;
            else if (i < STAGE) xs[i] = v;
        }
        __syncthreads();

        const float* xp0 = xs + ph * HALO_W + pw;
        #pragma unroll 4
        for (int c = 0; c < CG; ++c) {
            const float* xp = xp0 + c * CH_STRIDE;
            float xv[9];
            #pragma unroll
            for (int kh = 0; kh < 3; ++kh)
                #pragma unroll
                for (int kw = 0; kw < 3; ++kw)
                    xv[kh * 3 + kw] = xp[kh * HALO_W + kw];
            #pragma unroll
            for (int oo = 0; oo < OT; ++oo) {
                const float* wp = wb + (oo * CIN + c0 + cg + c) * 9;  // uniform
                #pragma unroll
                for (int t = 0; t < 9; ++t)
                    acc[oo] += min_ws(xv[t], wp[t]);
            }
        }
    }

    float* pb = part + cs * OUTN + (b * OCH + o0) * IMG + (h0 + ph) * WW + pw;
    #pragma unroll
    for (int oo = 0; oo < OT; ++oo)
        pb[oo * IMG] = acc[oo];
}

// out[i] = mu * (part0[i] + part1[i]); float4 over 802816 elems.
__global__ __launch_bounds__(256) void combine_kernel(const float* __restrict__ ws,
                                                      float* __restrict__ out) {
    const float mu = ws[0] * (1.0f / (float)NW);
    const float* p = ws + WSOFF;
    int i = (blockIdx.x * 256 + threadIdx.x) * 4;   // 784 blocks, exact
    float4 a = *reinterpret_cast<const float4*>(p + i);
    float4 c = *reinterpret_cast<const float4*>(p + OUTN + i);
    float4 r;
    r.x = mu * (a.x + c.x);
    r.y = mu * (a.y + c.y);
    r.z = mu * (a.z + c.z);
    r.w = mu * (a.w + c.w);
    *reinterpret_cast<float4*>(out + i) = r;
}

extern "C" void kernel_launch(void* const* d_in, const int* in_sizes, int n_in,
                              void* d_out, int out_size, void* d_ws, size_t ws_size,
                              hipStream_t stream) {
    const float* x   = (const float*)d_in[0];   // 4*32*56*56
    const float* w   = (const float*)d_in[1];   // 64*32*3*3
    float*       out = (float*)d_out;           // 4*64*56*56
    float*       ws  = (float*)d_ws;

    hipMemsetAsync(ws, 0, sizeof(float), stream);
    absmean_reduce<<<NW / (256 * 4), 256, 0, stream>>>(w, ws);
    dim3 grid(HH / TH, OCH / OT, BB * 2);       // 7 x 16 x 8 = 896 blocks
    minconv_kernel<<<grid, NT, 0, stream>>>(x, w, ws + WSOFF);
    combine_kernel<<<OUTN / (256 * 4), 256, 0, stream>>>(ws, out);
}